// Round 2
// 355.577 us; speedup vs baseline: 1.0484x; 1.0484x over previous
//
#include <hip/hip_runtime.h>
#include <hip/hip_bf16.h>
#include <stdint.h>

// Problem dims (fixed by reference)
#define M_TOT 16384   // B*S rows of x
#define K_TOT 2048    // contraction dim (M_DIM)
#define N_TOT 2048    // output cols (N_DIM)

// 256x256 8-phase GEMM geometry
#define BM 256
#define BN 256
#define BK 64
#define LDS_HALF (128 * 64)   // shorts per half-tile [128 rows][64 k]

#define W_BLOCKS 2048      // aux kernel: blocks [0, 2048) build W rows
#define CAST_BLOCKS 16384  // aux kernel: blocks [2048, 18432) cast x

typedef __attribute__((ext_vector_type(8))) short short8;
typedef __attribute__((ext_vector_type(4))) float float4v;
typedef __attribute__((ext_vector_type(8))) unsigned short ushort8;

__device__ __forceinline__ unsigned short f2bf_rne(float f) {
    union { float f; unsigned u; } a; a.f = f;
    unsigned r = a.u + 0x7FFFu + ((a.u >> 16) & 1u);  // round-to-nearest-even
    return (unsigned short)(r >> 16);
}

// ---- Aux kernel: W densify (zero+scatter) AND x fp32->bf16 cast, one dispatch ----
__global__ void prep_kernel(const float* __restrict__ x,
                            const float* __restrict__ val, const int* __restrict__ idx,
                            const int* __restrict__ indptr,
                            unsigned short* __restrict__ xb, unsigned short* __restrict__ Wb) {
    const int b = blockIdx.x;
    if (b < W_BLOCKS) {
        const int n = b;
        unsigned short* row = Wb + (size_t)n * K_TOT;
        ushort8 z = {0, 0, 0, 0, 0, 0, 0, 0};
        ((ushort8*)row)[threadIdx.x] = z;
        __syncthreads();
        const int s = indptr[n], e = indptr[n + 1];
        for (int j = s + (int)threadIdx.x; j < e; j += (int)blockDim.x)
            row[idx[j]] = f2bf_rne(val[j]);
    } else {
        const int i = (b - W_BLOCKS) * 256 + (int)threadIdx.x;  // 8-float chunk id
        const float4* xf = (const float4*)x;
        float4 a = xf[2 * i];
        float4 c = xf[2 * i + 1];
        ushort8 o;
        o[0] = f2bf_rne(a.x); o[1] = f2bf_rne(a.y); o[2] = f2bf_rne(a.z); o[3] = f2bf_rne(a.w);
        o[4] = f2bf_rne(c.x); o[5] = f2bf_rne(c.y); o[6] = f2bf_rne(c.z); o[7] = f2bf_rne(c.w);
        ((ushort8*)xb)[i] = o;
    }
}

// ---- 256x256 8-phase GEMM (primary path): C = A * W^T + bias ----
// 512 threads = 8 waves (2 wrow x 4 wcol), per-wave 128x64 output interleaved
// so each phase reads exactly ONE A-half and ONE B-half. 128 KiB LDS
// double-buffered; counted vmcnt(4) in the main loop (never drained to 0).
// Swizzle: LDS slot s of row r holds global 16B-chunk s^(r&7) (encoded in the
// global_load_lds SOURCE address; LDS dest stays lane-linear). Readers use
// slot = chunk ^ (r&7). This scheme measured SQ_LDS_BANK_CONFLICT = 0.
__global__ __launch_bounds__(512, 2) void gemm_bias_kernel_256(
    const unsigned short* __restrict__ A,   // [M_TOT][K_TOT] bf16
    const unsigned short* __restrict__ Bw,  // [N_TOT][K_TOT] bf16
    const float* __restrict__ bias,         // [N_TOT]
    float* __restrict__ C)                  // [M_TOT][N_TOT] fp32
{
    extern __shared__ unsigned short lds[];  // 131072 B dynamic

    const int tid  = threadIdx.x;
    const int lane = tid & 63;
    const int wave = tid >> 6;              // 0..7

    // XCD-aware bijective swizzle: 512 blocks, 64 per XCD, bn fastest inside
    const int raw = blockIdx.x;
    const int lid = (raw & 7) * 64 + (raw >> 3);
    const int bm = lid >> 3;                // 0..63
    const int bn = lid & 7;                 // 0..7

    const int wrow = wave >> 2;             // 0..1
    const int wcol = wave & 3;              // 0..3
    const int wr16 = wrow * 16;
    const int wc16 = wcol * 16;
    const int mrow = lane & 15;
    const int quad = lane >> 4;
    const int rx   = mrow & 7;              // row&7 for swizzle (all bases %8==0)

    // staging: per global_load_lds, wave covers 8 rows x 8 chunks of 16B;
    // source chunk = (lane&7)^(row&7) pre-swizzled, LDS dest lane-linear.
    const int srow = lane >> 3;                     // 0..7
    const int csrc = ((lane & 7) ^ srow) * 8;       // bf16 elem offset in row
    const unsigned short* pA = A  + (size_t)(bm * BM + wave * 8 + srow) * K_TOT + csrc;
    const unsigned short* pB = Bw + (size_t)(bn * BN + wave * 8 + srow) * K_TOT + csrc;
    unsigned short* lw = lds + wave * 8 * 64;       // per-wave LDS row base

    float4v acc[8][4] = {};

#define STAGE(PG, MATIDX, BUF, H, K0)                                            \
    { _Pragma("unroll")                                                          \
      for (int l = 0; l < 2; ++l) {                                              \
        const unsigned short* g = (PG) + ((size_t)((H) * 128 + l * 64) * K_TOT + (size_t)(K0)); \
        unsigned short* lp = lw + (((BUF) * 4 + (MATIDX) * 2 + (H)) * LDS_HALF) + l * 64 * 64;  \
        __builtin_amdgcn_global_load_lds(                                        \
            (const __attribute__((address_space(1))) unsigned int*)g,            \
            (__attribute__((address_space(3))) unsigned int*)lp, 16, 0, 0);      \
      } }

#define WAITV4 asm volatile("s_waitcnt vmcnt(4)" ::: "memory")
#define WAITV0 asm volatile("s_waitcnt vmcnt(0)" ::: "memory")
#define NOSTG  ((void)0)
#define NOWT   ((void)0)

#define PHASE(BUF, MH, NH, STG, TAILW)                                           \
  {                                                                              \
    const unsigned short* Ah = lds + ((BUF) * 4 + (MH)) * LDS_HALF;              \
    const unsigned short* Bh = lds + ((BUF) * 4 + 2 + (NH)) * LDS_HALF;          \
    short8 af[4][2], bfr[2][2];                                                  \
    _Pragma("unroll")                                                            \
    for (int mi = 0; mi < 4; ++mi) {                                             \
      const int r = mi * 32 + wr16 + mrow;                                       \
      _Pragma("unroll")                                                          \
      for (int ks = 0; ks < 2; ++ks)                                             \
        af[mi][ks] = *(const short8*)(Ah + r * 64 + (((ks * 4 + quad) ^ rx) * 8)); \
    }                                                                            \
    _Pragma("unroll")                                                            \
    for (int ni = 0; ni < 2; ++ni) {                                             \
      const int r = ni * 64 + wc16 + mrow;                                       \
      _Pragma("unroll")                                                          \
      for (int ks = 0; ks < 2; ++ks)                                             \
        bfr[ni][ks] = *(const short8*)(Bh + r * 64 + (((ks * 4 + quad) ^ rx) * 8)); \
    }                                                                            \
    STG;                                                                         \
    asm volatile("" ::: "memory");                                               \
    __builtin_amdgcn_s_barrier();                                                \
    asm volatile("s_waitcnt lgkmcnt(0)" ::: "memory");                           \
    __builtin_amdgcn_s_setprio(1);                                               \
    _Pragma("unroll")                                                            \
    for (int mi = 0; mi < 4; ++mi)                                               \
      _Pragma("unroll")                                                          \
      for (int ni = 0; ni < 2; ++ni)                                             \
        _Pragma("unroll")                                                        \
        for (int ks = 0; ks < 2; ++ks)                                           \
          acc[(MH) * 4 + mi][(NH) * 2 + ni] =                                    \
              __builtin_amdgcn_mfma_f32_16x16x32_bf16(                           \
                  af[mi][ks], bfr[ni][ks], acc[(MH) * 4 + mi][(NH) * 2 + ni], 0, 0, 0); \
    __builtin_amdgcn_s_setprio(0);                                               \
    TAILW;                                                                       \
    asm volatile("" ::: "memory");                                               \
    __builtin_amdgcn_s_barrier();                                                \
    asm volatile("" ::: "memory");                                               \
  }

    // prologue: tile0 -> buf0 (A0,B1,B0,A1); tile1 -> buf1 (A0,B1)
    STAGE(pA, 0, 0, 0, 0);
    STAGE(pB, 1, 0, 1, 0);
    STAGE(pB, 1, 0, 0, 0);
    STAGE(pA, 0, 0, 1, 0);
    STAGE(pA, 0, 1, 0, 64);
    STAGE(pB, 1, 1, 1, 64);
    WAITV4;  // tile0's 8 loads landed; tile1's 2 half-tiles may fly
    asm volatile("" ::: "memory");
    __builtin_amdgcn_s_barrier();
    asm volatile("" ::: "memory");

    int k0b = 64, k0c = 128, k0d = 192;   // k offsets of tiles T+1, T+2, T+3
#pragma unroll 1
    for (int it = 0; it < 15; ++it) {
        PHASE(0, 0, 0, STAGE(pB, 1, 1, 0, k0b), NOWT)
        PHASE(0, 0, 1, STAGE(pA, 0, 1, 1, k0b), NOWT)
        PHASE(0, 1, 1, STAGE(pA, 0, 0, 0, k0c), NOWT)
        PHASE(0, 1, 0, STAGE(pB, 1, 0, 1, k0c), WAITV4)
        PHASE(1, 0, 0, STAGE(pB, 1, 0, 0, k0c), NOWT)
        PHASE(1, 0, 1, STAGE(pA, 0, 0, 1, k0c), NOWT)
        PHASE(1, 1, 1, STAGE(pA, 0, 1, 0, k0d), NOWT)
        PHASE(1, 1, 0, STAGE(pB, 1, 1, 1, k0d), WAITV4)
        k0b += 128; k0c += 128; k0d += 128;
    }
    // tail iteration: tiles 30 (buf0) and 31 (buf1); k0b == 1984 here
    PHASE(0, 0, 0, STAGE(pB, 1, 1, 0, k0b), NOWT)
    PHASE(0, 0, 1, STAGE(pA, 0, 1, 1, k0b), NOWT)
    PHASE(0, 1, 1, NOSTG, NOWT)
    PHASE(0, 1, 0, NOSTG, WAITV0)
    PHASE(1, 0, 0, NOSTG, NOWT)
    PHASE(1, 0, 1, NOSTG, NOWT)
    PHASE(1, 1, 1, NOSTG, NOWT)
    PHASE(1, 1, 0, NOSTG, NOWT)

    // epilogue: C/D layout col = lane&15 (n), row = quad*4 + reg (m); fuse bias
#pragma unroll
    for (int nh = 0; nh < 2; ++nh)
#pragma unroll
        for (int ni = 0; ni < 2; ++ni) {
            const int col = bn * BN + nh * 128 + ni * 64 + wc16 + mrow;
            const float bv = bias[col];
#pragma unroll
            for (int mh = 0; mh < 2; ++mh)
#pragma unroll
                for (int mi = 0; mi < 4; ++mi) {
                    const int row0 = bm * BM + mh * 128 + mi * 32 + wr16 + quad * 4;
#pragma unroll
                    for (int r = 0; r < 4; ++r)
                        C[(size_t)(row0 + r) * N_TOT + col] =
                            acc[mh * 4 + mi][nh * 2 + ni][r] + bv;
                }
        }
#undef PHASE
#undef STAGE
#undef WAITV4
#undef WAITV0
#undef NOSTG
#undef NOWT
}

// ---- Fallback GEMM (proven round-0 kernel, 32 KiB static LDS, 372 µs total) ----
#define FBM 128
#define FBN 128
#define FBK 64
__global__ __launch_bounds__(256) void gemm_bias_kernel_128(
    const unsigned short* __restrict__ A,
    const unsigned short* __restrict__ Bw,
    const float* __restrict__ bias,
    float* __restrict__ C)
{
    __shared__ unsigned short Asm[FBM * FBK];
    __shared__ unsigned short Bsm[FBN * FBK];

    const int tid  = threadIdx.x;
    const int lane = tid & 63;
    const int wave = tid >> 6;
    const int bm = blockIdx.y;
    const int bn = blockIdx.x;

    const int srow_l = lane >> 3;
    const int schunk = ((lane & 7) ^ srow_l) * 8;
    const unsigned short* a_g[4];
    const unsigned short* b_g[4];
    unsigned short* a_l[4];
    unsigned short* b_l[4];
#pragma unroll
    for (int l = 0; l < 4; ++l) {
        const int row = wave * 32 + l * 8 + srow_l;
        a_g[l] = A  + (size_t)(bm * FBM + row) * K_TOT + schunk;
        b_g[l] = Bw + (size_t)(bn * FBN + row) * K_TOT + schunk;
        a_l[l] = Asm + (wave * 32 + l * 8) * FBK;
        b_l[l] = Bsm + (wave * 32 + l * 8) * FBK;
    }

    const int wm = (wave >> 1) * 64;
    const int wn = (wave & 1) * 64;
    const int mrow = lane & 15;
    const int quad = lane >> 4;
    const int rx   = mrow & 7;

    float4v acc[4][4] = {};

    for (int k0 = 0; k0 < K_TOT; k0 += FBK) {
        __syncthreads();
#pragma unroll
        for (int l = 0; l < 4; ++l)
            __builtin_amdgcn_global_load_lds(
                (const __attribute__((address_space(1))) unsigned int*)(a_g[l] + k0),
                (__attribute__((address_space(3))) unsigned int*)a_l[l], 16, 0, 0);
#pragma unroll
        for (int l = 0; l < 4; ++l)
            __builtin_amdgcn_global_load_lds(
                (const __attribute__((address_space(1))) unsigned int*)(b_g[l] + k0),
                (__attribute__((address_space(3))) unsigned int*)b_l[l], 16, 0, 0);
        __syncthreads();

#pragma unroll
        for (int ks = 0; ks < 2; ++ks) {
            short8 af[4], bf_[4];
#pragma unroll
            for (int mi = 0; mi < 4; ++mi) {
                const int r = wm + mi * 16 + mrow;
                const int slot = (ks * 4 + quad) ^ rx;
                af[mi] = *(const short8*)(Asm + r * FBK + slot * 8);
            }
#pragma unroll
            for (int ni = 0; ni < 4; ++ni) {
                const int r = wn + ni * 16 + mrow;
                const int slot = (ks * 4 + quad) ^ rx;
                bf_[ni] = *(const short8*)(Bsm + r * FBK + slot * 8);
            }
#pragma unroll
            for (int mi = 0; mi < 4; ++mi)
#pragma unroll
                for (int ni = 0; ni < 4; ++ni)
                    acc[mi][ni] = __builtin_amdgcn_mfma_f32_16x16x32_bf16(
                        af[mi], bf_[ni], acc[mi][ni], 0, 0, 0);
        }
    }

#pragma unroll
    for (int ni = 0; ni < 4; ++ni) {
        const int col = bn * FBN + wn + ni * 16 + mrow;
        const float bv = bias[col];
#pragma unroll
        for (int mi = 0; mi < 4; ++mi) {
#pragma unroll
            for (int r = 0; r < 4; ++r) {
                const int row = bm * FBM + wm + mi * 16 + quad * 4 + r;
                C[(size_t)row * N_TOT + col] = acc[mi][ni][r] + bv;
            }
        }
    }
}

extern "C" void kernel_launch(void* const* d_in, const int* in_sizes, int n_in,
                              void* d_out, int out_size, void* d_ws, size_t ws_size,
                              hipStream_t stream) {
    const float* x       = (const float*)d_in[0];
    const float* W_val   = (const float*)d_in[1];
    const float* bias    = (const float*)d_in[2];
    const int*   indices = (const int*)d_in[3];
    const int*   indptr  = (const int*)d_in[4];
    float* out = (float*)d_out;

    // workspace: [x_bf16: 16384*2048*2 = 64 MiB][W_bf16: 2048*2048*2 = 8 MiB]
    unsigned short* xb = (unsigned short*)d_ws;
    unsigned short* Wb = xb + (size_t)M_TOT * K_TOT;
    if (ws_size < ((size_t)M_TOT * K_TOT + (size_t)N_TOT * K_TOT) * sizeof(unsigned short))
        return;

    // 128 KiB dynamic LDS requires raising the attribute. Host-side config
    // call (not a stream op) — allowed under graph capture. If it fails, use
    // the proven 128^2 kernel instead of risking a launch failure.
    hipError_t attr_ok = hipFuncSetAttribute(
        reinterpret_cast<const void*>(gemm_bias_kernel_256),
        hipFuncAttributeMaxDynamicSharedMemorySize, 131072);

    // 1) fused prep: densify W + cast x (one dispatch)
    prep_kernel<<<W_BLOCKS + CAST_BLOCKS, 256, 0, stream>>>(x, W_val, indices, indptr, xb, Wb);

    // 2) GEMM + bias
    if (attr_ok == hipSuccess) {
        gemm_bias_kernel_256<<<dim3(512), 512, 131072, stream>>>(xb, Wb, bias, out);
    } else {
        dim3 grid(N_TOT / FBN, M_TOT / FBM);  // (16, 128)
        gemm_bias_kernel_128<<<grid, 256, 0, stream>>>(xb, Wb, bias, out);
    }
}

// Round 3
// 347.988 us; speedup vs baseline: 1.0713x; 1.0218x over previous
//
#include <hip/hip_runtime.h>
#include <hip/hip_bf16.h>
#include <stdint.h>

// Problem dims (fixed by reference)
#define M_TOT 16384   // B*S rows of x
#define K_TOT 2048    // contraction dim (M_DIM)
#define N_TOT 2048    // output cols (N_DIM)

// 256x256 8-phase GEMM geometry
#define BM 256
#define BN 256
#define BK 64
#define LDS_HALF (128 * 64)   // shorts per half-tile [128 rows][64 k]

typedef __attribute__((ext_vector_type(8))) short short8;
typedef __attribute__((ext_vector_type(4))) float float4v;
typedef __attribute__((ext_vector_type(8))) unsigned short ushort8;
typedef __attribute__((ext_vector_type(4))) unsigned short ushort4v;

__device__ __forceinline__ unsigned short f2bf_rne(float f) {
    union { float f; unsigned u; } a; a.f = f;
    unsigned r = a.u + 0x7FFFu + ((a.u >> 16) & 1u);  // round-to-nearest-even
    return (unsigned short)(r >> 16);
}

// ---- W densify: one block per row, zero 4KB then scatter nnz ----
__global__ __launch_bounds__(256) void densify_kernel(
    const float* __restrict__ val, const int* __restrict__ idx,
    const int* __restrict__ indptr, unsigned short* __restrict__ Wb) {
    const int n = blockIdx.x;
    unsigned short* row = Wb + (size_t)n * K_TOT;
    ushort8 z = {0, 0, 0, 0, 0, 0, 0, 0};
    ((ushort8*)row)[threadIdx.x] = z;
    __syncthreads();
    const int s = indptr[n], e = indptr[n + 1];
    for (int j = s + (int)threadIdx.x; j < e; j += (int)blockDim.x)
        row[idx[j]] = f2bf_rne(val[j]);
}

// ---- x cast: grid-stride, 1 contiguous float4 load + ushort4 store per lane ----
#define CAST_GRID 2048
__global__ __launch_bounds__(256) void cast_kernel(
    const float* __restrict__ x, unsigned short* __restrict__ xb) {
    const float4* xf = (const float4*)x;
    size_t i = (size_t)blockIdx.x * 256 + threadIdx.x;
    const size_t stride = (size_t)CAST_GRID * 256;
    // total float4 groups = 16384*2048/4 = 8,388,608 = stride * 16 exactly
#pragma unroll
    for (int it = 0; it < 16; ++it, i += stride) {
        float4 a = xf[i];
        ushort4v o;
        o[0] = f2bf_rne(a.x); o[1] = f2bf_rne(a.y);
        o[2] = f2bf_rne(a.z); o[3] = f2bf_rne(a.w);
        ((ushort4v*)xb)[i] = o;
    }
}

// ---- 256x256 8-phase GEMM (primary path): C = A * W^T + bias ----
// 512 threads = 8 waves (2 wrow x 4 wcol). Gray-code phase order per buffer
// ((A0,B0)->(A0,B1)->(A1,B1)->(A1,B0)) with PERSISTENT register fragments:
// only the operand that changes is re-read from LDS (12,4,8,4 ds_read_b128
// per phase instead of 12,12,12,12). This drops per-CU LDS read traffic below
// the MFMA pipe time (was 768 cyc LDS vs 512 cyc MFMA per phase -> LDS-bound).
// Counted vmcnt(4) in main loop; LDS slot s of row r holds global chunk
// s^(r&7) (swizzle in global source addr; LDS dest lane-linear; 0 conflicts).
__global__ __launch_bounds__(512, 2) void gemm_bias_kernel_256(
    const unsigned short* __restrict__ A,   // [M_TOT][K_TOT] bf16
    const unsigned short* __restrict__ Bw,  // [N_TOT][K_TOT] bf16
    const float* __restrict__ bias,         // [N_TOT]
    float* __restrict__ C)                  // [M_TOT][N_TOT] fp32
{
    extern __shared__ unsigned short lds[];  // 131072 B dynamic

    const int tid  = threadIdx.x;
    const int lane = tid & 63;
    const int wave = tid >> 6;              // 0..7

    // XCD-aware bijective swizzle: 512 blocks, 64 per XCD, bn fastest inside
    const int raw = blockIdx.x;
    const int lid = (raw & 7) * 64 + (raw >> 3);
    const int bm = lid >> 3;                // 0..63
    const int bn = lid & 7;                 // 0..7

    const int wrow = wave >> 2;             // 0..1
    const int wcol = wave & 3;              // 0..3
    const int wr16 = wrow * 16;
    const int wc16 = wcol * 16;
    const int mrow = lane & 15;
    const int quad = lane >> 4;
    const int rx   = mrow & 7;              // row&7 for swizzle (bases %8==0)

    // staging: per global_load_lds, wave covers 8 rows x 8 chunks of 16B;
    // source chunk = (lane&7)^(row&7) pre-swizzled, LDS dest lane-linear.
    const int srow = lane >> 3;                     // 0..7
    const int csrc = ((lane & 7) ^ srow) * 8;       // bf16 elem offset in row
    const unsigned short* pA = A  + (size_t)(bm * BM + wave * 8 + srow) * K_TOT + csrc;
    const unsigned short* pB = Bw + (size_t)(bn * BN + wave * 8 + srow) * K_TOT + csrc;
    unsigned short* lw = lds + wave * 8 * 64;       // per-wave LDS row base

    float4v acc[8][4] = {};
    short8 af[4][2];    // persistent A fragments (one A-half)
    short8 bfr[2][2];   // persistent B fragments (one B-half)

#define STAGE(PG, MATIDX, BUF, H, K0)                                            \
    { _Pragma("unroll")                                                          \
      for (int l = 0; l < 2; ++l) {                                              \
        const unsigned short* g = (PG) + ((size_t)((H) * 128 + l * 64) * K_TOT + (size_t)(K0)); \
        unsigned short* lp = lw + (((BUF) * 4 + (MATIDX) * 2 + (H)) * LDS_HALF) + l * 64 * 64;  \
        __builtin_amdgcn_global_load_lds(                                        \
            (const __attribute__((address_space(1))) unsigned int*)g,            \
            (__attribute__((address_space(3))) unsigned int*)lp, 16, 0, 0);      \
      } }

#define WAITV4 asm volatile("s_waitcnt vmcnt(4)" ::: "memory")
#define WAITV0 asm volatile("s_waitcnt vmcnt(0)" ::: "memory")
#define NOSTG  ((void)0)
#define NOWT   ((void)0)

#define PHASE(BUF, MH, NH, DOA, DOB, STG, TAILW)                                 \
  {                                                                              \
    if (DOA) {                                                                   \
      const unsigned short* Ah = lds + ((BUF) * 4 + (MH)) * LDS_HALF;            \
      _Pragma("unroll")                                                          \
      for (int mi = 0; mi < 4; ++mi) {                                           \
        const int r = mi * 32 + wr16 + mrow;                                     \
        _Pragma("unroll")                                                        \
        for (int ks = 0; ks < 2; ++ks)                                           \
          af[mi][ks] = *(const short8*)(Ah + r * 64 + (((ks * 4 + quad) ^ rx) * 8)); \
      }                                                                          \
    }                                                                            \
    if (DOB) {                                                                   \
      const unsigned short* Bh = lds + ((BUF) * 4 + 2 + (NH)) * LDS_HALF;        \
      _Pragma("unroll")                                                          \
      for (int ni = 0; ni < 2; ++ni) {                                           \
        const int r = ni * 64 + wc16 + mrow;                                     \
        _Pragma("unroll")                                                        \
        for (int ks = 0; ks < 2; ++ks)                                           \
          bfr[ni][ks] = *(const short8*)(Bh + r * 64 + (((ks * 4 + quad) ^ rx) * 8)); \
      }                                                                          \
    }                                                                            \
    STG;                                                                         \
    asm volatile("" ::: "memory");                                               \
    __builtin_amdgcn_s_barrier();                                                \
    asm volatile("s_waitcnt lgkmcnt(0)" ::: "memory");                           \
    __builtin_amdgcn_s_setprio(1);                                               \
    _Pragma("unroll")                                                            \
    for (int mi = 0; mi < 4; ++mi)                                               \
      _Pragma("unroll")                                                          \
      for (int ni = 0; ni < 2; ++ni)                                             \
        _Pragma("unroll")                                                        \
        for (int ks = 0; ks < 2; ++ks)                                           \
          acc[(MH) * 4 + mi][(NH) * 2 + ni] =                                    \
              __builtin_amdgcn_mfma_f32_16x16x32_bf16(                           \
                  af[mi][ks], bfr[ni][ks], acc[(MH) * 4 + mi][(NH) * 2 + ni], 0, 0, 0); \
    __builtin_amdgcn_s_setprio(0);                                               \
    TAILW;                                                                       \
    asm volatile("" ::: "memory");                                               \
    __builtin_amdgcn_s_barrier();                                                \
    asm volatile("" ::: "memory");                                               \
  }

    // prologue: tile0 -> buf0 (A0,B1,B0,A1); tile1 -> buf1 (A0,B1)
    STAGE(pA, 0, 0, 0, 0);
    STAGE(pB, 1, 0, 1, 0);
    STAGE(pB, 1, 0, 0, 0);
    STAGE(pA, 0, 0, 1, 0);
    STAGE(pA, 0, 1, 0, 64);
    STAGE(pB, 1, 1, 1, 64);
    WAITV4;  // tile0's 8 loads landed; tile1's 2 half-tiles may fly
    asm volatile("" ::: "memory");
    __builtin_amdgcn_s_barrier();
    asm volatile("" ::: "memory");

    int k0b = 64, k0c = 128, k0d = 192;   // k offsets of tiles T+1, T+2, T+3
#pragma unroll 1
    for (int it = 0; it < 15; ++it) {
        PHASE(0, 0, 0, 1, 1, STAGE(pB, 1, 1, 0, k0b), NOWT)
        PHASE(0, 0, 1, 0, 1, STAGE(pA, 0, 1, 1, k0b), NOWT)
        PHASE(0, 1, 1, 1, 0, STAGE(pA, 0, 0, 0, k0c), NOWT)
        PHASE(0, 1, 0, 0, 1, STAGE(pB, 1, 0, 1, k0c), WAITV4)
        PHASE(1, 0, 0, 1, 1, STAGE(pB, 1, 0, 0, k0c), NOWT)
        PHASE(1, 0, 1, 0, 1, STAGE(pA, 0, 0, 1, k0c), NOWT)
        PHASE(1, 1, 1, 1, 0, STAGE(pA, 0, 1, 0, k0d), NOWT)
        PHASE(1, 1, 0, 0, 1, STAGE(pB, 1, 1, 1, k0d), WAITV4)
        k0b += 128; k0c += 128; k0d += 128;
    }
    // tail iteration: tiles 30 (buf0) and 31 (buf1); k0b == 1984 here
    PHASE(0, 0, 0, 1, 1, STAGE(pB, 1, 1, 0, k0b), NOWT)
    PHASE(0, 0, 1, 0, 1, STAGE(pA, 0, 1, 1, k0b), NOWT)
    PHASE(0, 1, 1, 1, 0, NOSTG, NOWT)
    PHASE(0, 1, 0, 0, 1, NOSTG, WAITV0)
    PHASE(1, 0, 0, 1, 1, NOSTG, NOWT)
    PHASE(1, 0, 1, 0, 1, NOSTG, NOWT)
    PHASE(1, 1, 1, 1, 0, NOSTG, NOWT)
    PHASE(1, 1, 0, 0, 1, NOSTG, NOWT)

    // epilogue: C/D layout col = lane&15 (n), row = quad*4 + reg (m); fuse bias
#pragma unroll
    for (int nh = 0; nh < 2; ++nh)
#pragma unroll
        for (int ni = 0; ni < 2; ++ni) {
            const int col = bn * BN + nh * 128 + ni * 64 + wc16 + mrow;
            const float bv = bias[col];
#pragma unroll
            for (int mh = 0; mh < 2; ++mh)
#pragma unroll
                for (int mi = 0; mi < 4; ++mi) {
                    const int row0 = bm * BM + mh * 128 + mi * 32 + wr16 + quad * 4;
#pragma unroll
                    for (int r = 0; r < 4; ++r)
                        C[(size_t)(row0 + r) * N_TOT + col] =
                            acc[mh * 4 + mi][nh * 2 + ni][r] + bv;
                }
        }
#undef PHASE
#undef STAGE
#undef WAITV4
#undef WAITV0
#undef NOSTG
#undef NOWT
}

// ---- Fallback GEMM (proven 128^2 kernel, 32 KiB static LDS) ----
#define FBM 128
#define FBN 128
#define FBK 64
__global__ __launch_bounds__(256) void gemm_bias_kernel_128(
    const unsigned short* __restrict__ A,
    const unsigned short* __restrict__ Bw,
    const float* __restrict__ bias,
    float* __restrict__ C)
{
    __shared__ unsigned short Asm[FBM * FBK];
    __shared__ unsigned short Bsm[FBN * FBK];

    const int tid  = threadIdx.x;
    const int lane = tid & 63;
    const int wave = tid >> 6;
    const int bm = blockIdx.y;
    const int bn = blockIdx.x;

    const int srow_l = lane >> 3;
    const int schunk = ((lane & 7) ^ srow_l) * 8;
    const unsigned short* a_g[4];
    const unsigned short* b_g[4];
    unsigned short* a_l[4];
    unsigned short* b_l[4];
#pragma unroll
    for (int l = 0; l < 4; ++l) {
        const int row = wave * 32 + l * 8 + srow_l;
        a_g[l] = A  + (size_t)(bm * FBM + row) * K_TOT + schunk;
        b_g[l] = Bw + (size_t)(bn * FBN + row) * K_TOT + schunk;
        a_l[l] = Asm + (wave * 32 + l * 8) * FBK;
        b_l[l] = Bsm + (wave * 32 + l * 8) * FBK;
    }

    const int wm = (wave >> 1) * 64;
    const int wn = (wave & 1) * 64;
    const int mrow = lane & 15;
    const int quad = lane >> 4;
    const int rx   = mrow & 7;

    float4v acc[4][4] = {};

    for (int k0 = 0; k0 < K_TOT; k0 += FBK) {
        __syncthreads();
#pragma unroll
        for (int l = 0; l < 4; ++l)
            __builtin_amdgcn_global_load_lds(
                (const __attribute__((address_space(1))) unsigned int*)(a_g[l] + k0),
                (__attribute__((address_space(3))) unsigned int*)a_l[l], 16, 0, 0);
#pragma unroll
        for (int l = 0; l < 4; ++l)
            __builtin_amdgcn_global_load_lds(
                (const __attribute__((address_space(1))) unsigned int*)(b_g[l] + k0),
                (__attribute__((address_space(3))) unsigned int*)b_l[l], 16, 0, 0);
        __syncthreads();

#pragma unroll
        for (int ks = 0; ks < 2; ++ks) {
            short8 af[4], bf_[4];
#pragma unroll
            for (int mi = 0; mi < 4; ++mi) {
                const int r = wm + mi * 16 + mrow;
                const int slot = (ks * 4 + quad) ^ rx;
                af[mi] = *(const short8*)(Asm + r * FBK + slot * 8);
            }
#pragma unroll
            for (int ni = 0; ni < 4; ++ni) {
                const int r = wn + ni * 16 + mrow;
                const int slot = (ks * 4 + quad) ^ rx;
                bf_[ni] = *(const short8*)(Bsm + r * FBK + slot * 8);
            }
#pragma unroll
            for (int mi = 0; mi < 4; ++mi)
#pragma unroll
                for (int ni = 0; ni < 4; ++ni)
                    acc[mi][ni] = __builtin_amdgcn_mfma_f32_16x16x32_bf16(
                        af[mi], bf_[ni], acc[mi][ni], 0, 0, 0);
        }
    }

#pragma unroll
    for (int ni = 0; ni < 4; ++ni) {
        const int col = bn * FBN + wn + ni * 16 + mrow;
        const float bv = bias[col];
#pragma unroll
        for (int mi = 0; mi < 4; ++mi) {
#pragma unroll
            for (int r = 0; r < 4; ++r) {
                const int row = bm * FBM + wm + mi * 16 + quad * 4 + r;
                C[(size_t)row * N_TOT + col] = acc[mi][ni][r] + bv;
            }
        }
    }
}

extern "C" void kernel_launch(void* const* d_in, const int* in_sizes, int n_in,
                              void* d_out, int out_size, void* d_ws, size_t ws_size,
                              hipStream_t stream) {
    const float* x       = (const float*)d_in[0];
    const float* W_val   = (const float*)d_in[1];
    const float* bias    = (const float*)d_in[2];
    const int*   indices = (const int*)d_in[3];
    const int*   indptr  = (const int*)d_in[4];
    float* out = (float*)d_out;

    // workspace: [x_bf16: 16384*2048*2 = 64 MiB][W_bf16: 2048*2048*2 = 8 MiB]
    unsigned short* xb = (unsigned short*)d_ws;
    unsigned short* Wb = xb + (size_t)M_TOT * K_TOT;
    if (ws_size < ((size_t)M_TOT * K_TOT + (size_t)N_TOT * K_TOT) * sizeof(unsigned short))
        return;

    // 128 KiB dynamic LDS requires raising the attribute (host-side config
    // call, capture-safe). If it fails, fall back to the proven 128^2 kernel.
    hipError_t attr_ok = hipFuncSetAttribute(
        reinterpret_cast<const void*>(gemm_bias_kernel_256),
        hipFuncAttributeMaxDynamicSharedMemorySize, 131072);

    // 1) prep, split into two dispatches so each is visible in rocprof
    cast_kernel<<<CAST_GRID, 256, 0, stream>>>(x, xb);
    densify_kernel<<<N_TOT, 256, 0, stream>>>(W_val, indices, indptr, Wb);

    // 2) GEMM + bias
    if (attr_ok == hipSuccess) {
        gemm_bias_kernel_256<<<dim3(512), 512, 131072, stream>>>(xb, Wb, bias, out);
    } else {
        dim3 grid(N_TOT / FBN, M_TOT / FBM);  // (16, 128)
        gemm_bias_kernel_128<<<grid, 256, 0, stream>>>(xb, Wb, bias, out);
    }
}

// Round 5
// 346.845 us; speedup vs baseline: 1.0748x; 1.0033x over previous
//
#include <hip/hip_runtime.h>
#include <hip/hip_bf16.h>
#include <stdint.h>

// Problem dims (fixed by reference)
#define M_TOT 16384   // B*S rows of x
#define K_TOT 2048    // contraction dim (M_DIM)
#define N_TOT 2048    // output cols (N_DIM)

// 256x256 8-phase GEMM geometry
#define BM 256
#define BN 256
#define BK 64
#define LDS_HALF (128 * 64)   // shorts per half-tile [128 rows][64 k]

typedef __attribute__((ext_vector_type(8))) short short8;
typedef __attribute__((ext_vector_type(4))) float float4v;
typedef __attribute__((ext_vector_type(8))) unsigned short ushort8;
typedef __attribute__((ext_vector_type(4))) unsigned short ushort4v;

__device__ __forceinline__ unsigned short f2bf_rne(float f) {
    union { float f; unsigned u; } a; a.f = f;
    unsigned r = a.u + 0x7FFFu + ((a.u >> 16) & 1u);  // round-to-nearest-even
    return (unsigned short)(r >> 16);
}

// ---- W densify: one block per row, zero 4KB then scatter nnz ----
__global__ __launch_bounds__(256) void densify_kernel(
    const float* __restrict__ val, const int* __restrict__ idx,
    const int* __restrict__ indptr, unsigned short* __restrict__ Wb) {
    const int n = blockIdx.x;
    unsigned short* row = Wb + (size_t)n * K_TOT;
    ushort8 z = {0, 0, 0, 0, 0, 0, 0, 0};
    ((ushort8*)row)[threadIdx.x] = z;
    __syncthreads();
    const int s = indptr[n], e = indptr[n + 1];
    for (int j = s + (int)threadIdx.x; j < e; j += (int)blockDim.x)
        row[idx[j]] = f2bf_rne(val[j]);
}

// ---- x cast: grid-stride, 1 contiguous float4 load + ushort4 store per lane ----
#define CAST_GRID 2048
__global__ __launch_bounds__(256) void cast_kernel(
    const float* __restrict__ x, unsigned short* __restrict__ xb) {
    const float4* xf = (const float4*)x;
    size_t i = (size_t)blockIdx.x * 256 + threadIdx.x;
    const size_t stride = (size_t)CAST_GRID * 256;
    // total float4 groups = 16384*2048/4 = 8,388,608 = stride * 16 exactly
#pragma unroll
    for (int it = 0; it < 16; ++it, i += stride) {
        float4 a = xf[i];
        ushort4v o;
        o[0] = f2bf_rne(a.x); o[1] = f2bf_rne(a.y);
        o[2] = f2bf_rne(a.z); o[3] = f2bf_rne(a.w);
        ((ushort4v*)xb)[i] = o;
    }
}

// ---- 256x256 8-phase GEMM: C = A * W^T + bias ----
// 512 threads = 8 waves (2 wrow x 4 wcol), per-wave 128x64 output.
// READ-AHEAD schedule: each phase's LDS fragment reads are issued at the END
// of the previous phase (after its MFMA cluster), overlapping the matrix-pipe
// drain; lgkmcnt(0) at phase start is then ~free. One barrier per phase; an
// extra barrier only after the counted WAITV4 at p3/p7 (a wave's vmcnt tracks
// only its OWN loads, so reads of rows staged by other waves must follow a
// barrier that follows all waves' vmcnt-wait).
// Both B halves persist in regs (bfr[2]): 24 ds_read_b128 per K-tile per wave
// (A 16 + B 8), the decomposition minimum. Counted vmcnt(4) never drains to 0
// in the main loop. Swizzle: LDS slot s of row r holds global chunk s^(r&7)
// (pre-swizzled global source; LDS dest lane-linear; measured 0 conflicts).
//
// Per-iteration phase table (tiles T=2i buf0, T+1 buf1; STG = half staged,
// RD = fragments pre-read for the NEXT phase):
//   p0 (A0,B0) STG B0(T+1)->b1   RD B1<-b0
//   p1 (A0,B1) STG A1(T+1)->b1   RD A1<-b0
//   p2 (A1,B1) STG A0(T+2)->b0   --
//   p3 (A1,B0) STG B1(T+2)->b0   WAITV4+bar, RD A0,B0<-b1
//   p4 (A0,B0) STG B0(T+2)->b0   RD B1<-b1
//   p5 (A0,B1) STG A1(T+2)->b0   RD A1<-b1
//   p6 (A1,B1) STG A0(T+3)->b1   --
//   p7 (A1,B0) STG B1(T+3)->b1   WAITV4+bar, RD A0,B0<-b0
// vmcnt ledger: each buf-quad is entered with exactly 4 outstanding loads;
// WAITV4 after the quad's 4 stages confirms precisely the halves the next
// quad pre-reads. Every STAGE target is >=2 phases + >=1 barrier after its
// last reader's read-issue (hand-verified for all 8 targets).
__global__ __launch_bounds__(512, 2) void gemm_bias_kernel_256(
    const unsigned short* __restrict__ A,   // [M_TOT][K_TOT] bf16
    const unsigned short* __restrict__ Bw,  // [N_TOT][K_TOT] bf16
    const float* __restrict__ bias,         // [N_TOT]
    float* __restrict__ C)                  // [M_TOT][N_TOT] fp32
{
    extern __shared__ unsigned short lds[];  // 131072 B dynamic

    const int tid  = threadIdx.x;
    const int lane = tid & 63;
    const int wave = tid >> 6;              // 0..7

    // XCD-aware bijective swizzle: 512 blocks, 64 per XCD, bn fastest inside
    const int raw = blockIdx.x;
    const int lid = (raw & 7) * 64 + (raw >> 3);
    const int bm = lid >> 3;                // 0..63
    const int bn = lid & 7;                 // 0..7

    const int wrow = wave >> 2;             // 0..1
    const int wcol = wave & 3;              // 0..3
    const int wr16 = wrow * 16;
    const int wc16 = wcol * 16;
    const int mrow = lane & 15;
    const int quad = lane >> 4;
    const int rx   = mrow & 7;              // row&7 for swizzle (bases %8==0)

    // staging: per global_load_lds, wave covers 8 rows x 8 chunks of 16B;
    // source chunk = (lane&7)^(row&7) pre-swizzled, LDS dest lane-linear.
    const int srow = lane >> 3;                     // 0..7
    const int csrc = ((lane & 7) ^ srow) * 8;       // bf16 elem offset in row
    const unsigned short* pA = A  + (size_t)(bm * BM + wave * 8 + srow) * K_TOT + csrc;
    const unsigned short* pB = Bw + (size_t)(bn * BN + wave * 8 + srow) * K_TOT + csrc;
    unsigned short* lw = lds + wave * 8 * 64;       // per-wave LDS row base

    float4v acc[8][4] = {};
    short8 af[4][2];        // A fragments of the current A-half
    short8 bfr[2][2][2];    // B fragments, BOTH halves persistent [nh][ni][ks]

#define STAGE(PG, MATIDX, BUF, H, K0)                                            \
    { _Pragma("unroll")                                                          \
      for (int l = 0; l < 2; ++l) {                                              \
        const unsigned short* g = (PG) + ((size_t)((H) * 128 + l * 64) * K_TOT + (size_t)(K0)); \
        unsigned short* lp = lw + (((BUF) * 4 + (MATIDX) * 2 + (H)) * LDS_HALF) + l * 64 * 64;  \
        __builtin_amdgcn_global_load_lds(                                        \
            (const __attribute__((address_space(1))) unsigned int*)g,            \
            (__attribute__((address_space(3))) unsigned int*)lp, 16, 0, 0);      \
      } }

#define RD_A(RBUF, RMH)                                                          \
    { const unsigned short* Ah = lds + ((RBUF) * 4 + (RMH)) * LDS_HALF;          \
      _Pragma("unroll")                                                          \
      for (int mi = 0; mi < 4; ++mi) {                                           \
        const int r = mi * 32 + wr16 + mrow;                                     \
        _Pragma("unroll")                                                        \
        for (int ks = 0; ks < 2; ++ks)                                           \
          af[mi][ks] = *(const short8*)(Ah + r * 64 + (((ks * 4 + quad) ^ rx) * 8)); \
      } }

#define RD_B(RBUF, RNH)                                                          \
    { const unsigned short* Bh = lds + ((RBUF) * 4 + 2 + (RNH)) * LDS_HALF;      \
      _Pragma("unroll")                                                          \
      for (int ni = 0; ni < 2; ++ni) {                                           \
        const int r = ni * 64 + wc16 + mrow;                                     \
        _Pragma("unroll")                                                        \
        for (int ks = 0; ks < 2; ++ks)                                           \
          bfr[RNH][ni][ks] = *(const short8*)(Bh + r * 64 + (((ks * 4 + quad) ^ rx) * 8)); \
      } }

#define BARX { asm volatile("" ::: "memory"); __builtin_amdgcn_s_barrier(); asm volatile("" ::: "memory"); }
#define NOB  ((void)0);
#define WAITV4 asm volatile("s_waitcnt vmcnt(4)" ::: "memory")
#define WAITV0 asm volatile("s_waitcnt vmcnt(0)" ::: "memory")
#define WV4B { WAITV4; BARX }
#define WV0B { WAITV0; BARX }
#define NOWT ((void)0)
#define NOSTG ((void)0)
#define NORD ((void)0)

// PHASE: [BHEAD][lgkm0][MFMA cluster][stage][tail-wait][pre-reads for next]
#define PHASE(MH, NH, BHEAD, STG, TAILW, RDS)                                    \
  {                                                                              \
    BHEAD                                                                        \
    asm volatile("s_waitcnt lgkmcnt(0)" ::: "memory");                           \
    __builtin_amdgcn_s_setprio(1);                                               \
    _Pragma("unroll")                                                            \
    for (int mi = 0; mi < 4; ++mi)                                               \
      _Pragma("unroll")                                                          \
      for (int ni = 0; ni < 2; ++ni)                                             \
        _Pragma("unroll")                                                        \
        for (int ks = 0; ks < 2; ++ks)                                           \
          acc[(MH) * 4 + mi][(NH) * 2 + ni] =                                    \
              __builtin_amdgcn_mfma_f32_16x16x32_bf16(                           \
                  af[mi][ks], bfr[NH][ni][ks], acc[(MH) * 4 + mi][(NH) * 2 + ni], 0, 0, 0); \
    __builtin_amdgcn_s_setprio(0);                                               \
    STG;                                                                         \
    TAILW;                                                                       \
    RDS;                                                                         \
  }

    // prologue: tile0 -> buf0 (A0,B1,B0,A1); tile1 -> buf1 (A0,B1);
    // confirm buf0 (WAITV4 leaves buf1's 4 loads in flight), barrier, pre-read
    // p0's fragments. Entry state == steady-state quad entry (4 outstanding).
    STAGE(pA, 0, 0, 0, 0);
    STAGE(pB, 1, 0, 1, 0);
    STAGE(pB, 1, 0, 0, 0);
    STAGE(pA, 0, 0, 1, 0);
    STAGE(pA, 0, 1, 0, 64);
    STAGE(pB, 1, 1, 1, 64);
    WAITV4;
    BARX
    RD_A(0, 0); RD_B(0, 0);

    int k0b = 64, k0c = 128, k0d = 192;   // k offsets of tiles T+1, T+2, T+3
#pragma unroll 1
    for (int it = 0; it < 15; ++it) {
        PHASE(0, 0, NOB,  STAGE(pB, 1, 1, 0, k0b), NOWT, RD_B(0, 1))
        PHASE(0, 1, BARX, STAGE(pA, 0, 1, 1, k0b), NOWT, RD_A(0, 1))
        PHASE(1, 1, BARX, STAGE(pA, 0, 0, 0, k0c), NOWT, NORD)
        PHASE(1, 0, BARX, STAGE(pB, 1, 0, 1, k0c), WV4B, RD_A(1, 0); RD_B(1, 0))
        PHASE(0, 0, NOB,  STAGE(pB, 1, 0, 0, k0c), NOWT, RD_B(1, 1))
        PHASE(0, 1, BARX, STAGE(pA, 0, 0, 1, k0c), NOWT, RD_A(1, 1))
        PHASE(1, 1, BARX, STAGE(pA, 0, 1, 0, k0d), NOWT, NORD)
        PHASE(1, 0, BARX, STAGE(pB, 1, 1, 1, k0d), WV4B, RD_A(0, 0); RD_B(0, 0))
        k0b += 128; k0c += 128; k0d += 128;
    }
    // tail: tiles 30 (buf0) and 31 (buf1); k0b == 1984 = tile 31 B0/A1
    PHASE(0, 0, NOB,  STAGE(pB, 1, 1, 0, k0b), NOWT, RD_B(0, 1))
    PHASE(0, 1, BARX, STAGE(pA, 0, 1, 1, k0b), NOWT, RD_A(0, 1))
    PHASE(1, 1, BARX, NOSTG, NOWT, NORD)
    PHASE(1, 0, BARX, NOSTG, WV0B, RD_A(1, 0); RD_B(1, 0))
    PHASE(0, 0, NOB,  NOSTG, NOWT, RD_B(1, 1))
    PHASE(0, 1, BARX, NOSTG, NOWT, RD_A(1, 1))
    PHASE(1, 1, BARX, NOSTG, NOWT, NORD)
    PHASE(1, 0, BARX, NOSTG, NOWT, NORD)

    // epilogue: C/D layout col = lane&15 (n), row = quad*4 + reg (m); fuse bias
#pragma unroll
    for (int nh = 0; nh < 2; ++nh)
#pragma unroll
        for (int ni = 0; ni < 2; ++ni) {
            const int col = bn * BN + nh * 128 + ni * 64 + wc16 + mrow;
            const float bv = bias[col];
#pragma unroll
            for (int mh = 0; mh < 2; ++mh)
#pragma unroll
                for (int mi = 0; mi < 4; ++mi) {
                    const int row0 = bm * BM + mh * 128 + mi * 32 + wr16 + quad * 4;
#pragma unroll
                    for (int r = 0; r < 4; ++r)
                        C[(size_t)(row0 + r) * N_TOT + col] =
                            acc[mh * 4 + mi][nh * 2 + ni][r] + bv;
                }
        }
#undef PHASE
#undef STAGE
#undef RD_A
#undef RD_B
#undef BARX
#undef NOB
#undef WAITV4
#undef WAITV0
#undef WV4B
#undef WV0B
#undef NOWT
#undef NOSTG
#undef NORD
}

// ---- Fallback GEMM (proven 128^2 kernel, 32 KiB static LDS) ----
#define FBM 128
#define FBN 128
#define FBK 64
__global__ __launch_bounds__(256) void gemm_bias_kernel_128(
    const unsigned short* __restrict__ A,
    const unsigned short* __restrict__ Bw,
    const float* __restrict__ bias,
    float* __restrict__ C)
{
    __shared__ unsigned short Asm[FBM * FBK];
    __shared__ unsigned short Bsm[FBN * FBK];

    const int tid  = threadIdx.x;
    const int lane = tid & 63;
    const int wave = tid >> 6;
    const int bm = blockIdx.y;
    const int bn = blockIdx.x;

    const int srow_l = lane >> 3;
    const int schunk = ((lane & 7) ^ srow_l) * 8;
    const unsigned short* a_g[4];
    const unsigned short* b_g[4];
    unsigned short* a_l[4];
    unsigned short* b_l[4];
#pragma unroll
    for (int l = 0; l < 4; ++l) {
        const int row = wave * 32 + l * 8 + srow_l;
        a_g[l] = A  + (size_t)(bm * FBM + row) * K_TOT + schunk;
        b_g[l] = Bw + (size_t)(bn * FBN + row) * K_TOT + schunk;
        a_l[l] = Asm + (wave * 32 + l * 8) * FBK;
        b_l[l] = Bsm + (wave * 32 + l * 8) * FBK;
    }

    const int wm = (wave >> 1) * 64;
    const int wn = (wave & 1) * 64;
    const int mrow = lane & 15;
    const int quad = lane >> 4;
    const int rx   = mrow & 7;

    float4v acc[4][4] = {};

    for (int k0 = 0; k0 < K_TOT; k0 += FBK) {
        __syncthreads();
#pragma unroll
        for (int l = 0; l < 4; ++l)
            __builtin_amdgcn_global_load_lds(
                (const __attribute__((address_space(1))) unsigned int*)(a_g[l] + k0),
                (__attribute__((address_space(3))) unsigned int*)a_l[l], 16, 0, 0);
#pragma unroll
        for (int l = 0; l < 4; ++l)
            __builtin_amdgcn_global_load_lds(
                (const __attribute__((address_space(1))) unsigned int*)(b_g[l] + k0),
                (__attribute__((address_space(3))) unsigned int*)b_l[l], 16, 0, 0);
        __syncthreads();

#pragma unroll
        for (int ks = 0; ks < 2; ++ks) {
            short8 af[4], bf_[4];
#pragma unroll
            for (int mi = 0; mi < 4; ++mi) {
                const int r = wm + mi * 16 + mrow;
                const int slot = (ks * 4 + quad) ^ rx;
                af[mi] = *(const short8*)(Asm + r * FBK + slot * 8);
            }
#pragma unroll
            for (int ni = 0; ni < 4; ++ni) {
                const int r = wn + ni * 16 + mrow;
                const int slot = (ks * 4 + quad) ^ rx;
                bf_[ni] = *(const short8*)(Bsm + r * FBK + slot * 8);
            }
#pragma unroll
            for (int mi = 0; mi < 4; ++mi)
#pragma unroll
                for (int ni = 0; ni < 4; ++ni)
                    acc[mi][ni] = __builtin_amdgcn_mfma_f32_16x16x32_bf16(
                        af[mi], bf_[ni], acc[mi][ni], 0, 0, 0);
        }
    }

#pragma unroll
    for (int ni = 0; ni < 4; ++ni) {
        const int col = bn * FBN + wn + ni * 16 + mrow;
        const float bv = bias[col];
#pragma unroll
        for (int mi = 0; mi < 4; ++mi) {
#pragma unroll
            for (int r = 0; r < 4; ++r) {
                const int row = bm * FBM + wm + mi * 16 + quad * 4 + r;
                C[(size_t)row * N_TOT + col] = acc[mi][ni][r] + bv;
            }
        }
    }
}

extern "C" void kernel_launch(void* const* d_in, const int* in_sizes, int n_in,
                              void* d_out, int out_size, void* d_ws, size_t ws_size,
                              hipStream_t stream) {
    const float* x       = (const float*)d_in[0];
    const float* W_val   = (const float*)d_in[1];
    const float* bias    = (const float*)d_in[2];
    const int*   indices = (const int*)d_in[3];
    const int*   indptr  = (const int*)d_in[4];
    float* out = (float*)d_out;

    // workspace: [x_bf16: 16384*2048*2 = 64 MiB][W_bf16: 2048*2048*2 = 8 MiB]
    unsigned short* xb = (unsigned short*)d_ws;
    unsigned short* Wb = xb + (size_t)M_TOT * K_TOT;
    if (ws_size < ((size_t)M_TOT * K_TOT + (size_t)N_TOT * K_TOT) * sizeof(unsigned short))
        return;

    // 128 KiB dynamic LDS requires raising the attribute (host-side config
    // call, capture-safe). If it fails, fall back to the proven 128^2 kernel.
    hipError_t attr_ok = hipFuncSetAttribute(
        reinterpret_cast<const void*>(gemm_bias_kernel_256),
        hipFuncAttributeMaxDynamicSharedMemorySize, 131072);

    // 1) prep, split into two dispatches so each is visible in rocprof
    cast_kernel<<<CAST_GRID, 256, 0, stream>>>(x, xb);
    densify_kernel<<<N_TOT, 256, 0, stream>>>(W_val, indices, indptr, Wb);

    // 2) GEMM + bias
    if (attr_ok == hipSuccess) {
        gemm_bias_kernel_256<<<dim3(512), 512, 131072, stream>>>(xb, Wb, bias, out);
    } else {
        dim3 grid(N_TOT / FBN, M_TOT / FBM);  // (16, 128)
        gemm_bias_kernel_128<<<grid, 256, 0, stream>>>(xb, Wb, bias, out);
    }
}

// Round 6
// 337.634 us; speedup vs baseline: 1.1042x; 1.0273x over previous
//
#include <hip/hip_runtime.h>
#include <hip/hip_bf16.h>
#include <stdint.h>

// Problem dims (fixed by reference)
#define M_TOT 16384   // B*S rows of x
#define K_TOT 2048    // contraction dim (M_DIM)
#define N_TOT 2048    // output cols (N_DIM)

// 256x256 8-phase GEMM geometry
#define BM 256
#define BN 256
#define BK 64
#define LDS_HALF (128 * 64)   // shorts per half-tile [128 rows][64 k]

#define W_BLOCKS 2048      // prep: blocks [0, 2048) build W rows
#define CAST_BLOCKS 16384  // prep: blocks [2048, 18432) cast x

typedef __attribute__((ext_vector_type(8))) short short8;
typedef __attribute__((ext_vector_type(4))) float float4v;
typedef __attribute__((ext_vector_type(8))) unsigned short ushort8;

__device__ __forceinline__ unsigned short f2bf_rne(float f) {
    union { float f; unsigned u; } a; a.f = f;
    unsigned r = a.u + 0x7FFFu + ((a.u >> 16) & 1u);  // round-to-nearest-even
    return (unsigned short)(r >> 16);
}

// ---- Prep: W densify (zero+scatter) AND x fp32->bf16 cast, ONE dispatch ----
// (merged: one fewer launch; round-2 vs round-3 showed split cost ~15 us)
__global__ __launch_bounds__(256) void prep_kernel(
    const float* __restrict__ x,
    const float* __restrict__ val, const int* __restrict__ idx,
    const int* __restrict__ indptr,
    unsigned short* __restrict__ xb, unsigned short* __restrict__ Wb) {
    const int b = blockIdx.x;
    if (b < W_BLOCKS) {
        const int n = b;
        unsigned short* row = Wb + (size_t)n * K_TOT;
        ushort8 z = {0, 0, 0, 0, 0, 0, 0, 0};
        ((ushort8*)row)[threadIdx.x] = z;
        __syncthreads();
        const int s = indptr[n], e = indptr[n + 1];
        for (int j = s + (int)threadIdx.x; j < e; j += (int)blockDim.x)
            row[idx[j]] = f2bf_rne(val[j]);
    } else {
        const int i = (b - W_BLOCKS) * 256 + (int)threadIdx.x;  // 8-float chunk id
        const float4* xf = (const float4*)x;
        float4 a = xf[2 * i];
        float4 c = xf[2 * i + 1];
        ushort8 o;
        o[0] = f2bf_rne(a.x); o[1] = f2bf_rne(a.y); o[2] = f2bf_rne(a.z); o[3] = f2bf_rne(a.w);
        o[4] = f2bf_rne(c.x); o[5] = f2bf_rne(c.y); o[6] = f2bf_rne(c.z); o[7] = f2bf_rne(c.w);
        ((ushort8*)xb)[i] = o;
    }
}

// ---- 256x256 8-phase GEMM: C = A * W^T + bias ----
// 512 threads = 8 waves (2 wrow x 4 wcol), per-wave 128x64 output.
// INTERLEAVED-READ schedule (evolution of the round-5 read-ahead): the
// round-5 profile implies phase = 620 cyc MFMA-issue + ~500 cyc tail read
// burst (48 ds_read_b128/CU hit the LDS pipe after the fenced MFMA cluster,
// while the pipe idled during the cluster). Gray-code phase order means only
// ONE operand changes per phase, so the next phase's reads can go INSIDE the
// current MFMA cluster with ZERO extra registers:
//  - B-change phases (p0,p4): bfr[NH^1] is not read by this cluster -> one
//    read block after the mi=0 MFMA group.
//  - A-change phases (p1,p5): per-mi interleave [4 MFMAs on af[mi]]
//    [re-read af[mi]] — WAR preserved by program order, compiler-visible.
//  - p3/p7 reads are publication-gated by WV4B (cross-wave staging) and must
//    stay at the tail.
// lgkmcnt(0) at each phase head drains that phase's operand reads (issued
// >=1 phase earlier inside the previous cluster). Counted vmcnt(4) in the
// main loop (never 0). Swizzle: LDS slot s of row r holds global 16B-chunk
// s^(r&7) (pre-swizzled global source addr; LDS dest lane-linear; measured
// SQ_LDS_BANK_CONFLICT = 0).
//
// Staging schedule per iteration (tiles T=2i buf0, T+1 buf1) — unchanged
// from round 5 (vmcnt ledger: each buf-quad entered with exactly 4
// outstanding loads; WAITV4 after the quad's 4 stages confirms exactly the
// halves the next quad reads):
//   p0 STG B0(T+1)->b1   p1 STG A1(T+1)->b1   p2 STG A0(T+2)->b0
//   p3 STG B1(T+2)->b0 WV4B   p4 STG B0(T+2)->b0   p5 STG A1(T+2)->b0
//   p6 STG A0(T+3)->b1   p7 STG B1(T+3)->b1 WV4B
// Overwrite hazards: reads only moved EARLIER within their phase vs round 5,
// so all 8 stage-vs-last-reader margins (>=1 lgkm0 drain + >=1 barrier) hold.
__global__ __launch_bounds__(512, 2) void gemm_bias_kernel_256(
    const unsigned short* __restrict__ A,   // [M_TOT][K_TOT] bf16
    const unsigned short* __restrict__ Bw,  // [N_TOT][K_TOT] bf16
    const float* __restrict__ bias,         // [N_TOT]
    float* __restrict__ C)                  // [M_TOT][N_TOT] fp32
{
    extern __shared__ unsigned short lds[];  // 131072 B dynamic

    const int tid  = threadIdx.x;
    const int lane = tid & 63;
    const int wave = tid >> 6;              // 0..7

    // XCD-aware bijective swizzle: 512 blocks, 64 per XCD, bn fastest inside
    const int raw = blockIdx.x;
    const int lid = (raw & 7) * 64 + (raw >> 3);
    const int bm = lid >> 3;                // 0..63
    const int bn = lid & 7;                 // 0..7

    const int wrow = wave >> 2;             // 0..1
    const int wcol = wave & 3;              // 0..3
    const int wr16 = wrow * 16;
    const int wc16 = wcol * 16;
    const int mrow = lane & 15;
    const int quad = lane >> 4;
    const int rx   = mrow & 7;              // row&7 for swizzle (bases %8==0)

    // staging: per global_load_lds, wave covers 8 rows x 8 chunks of 16B;
    // source chunk = (lane&7)^(row&7) pre-swizzled, LDS dest lane-linear.
    const int srow = lane >> 3;                     // 0..7
    const int csrc = ((lane & 7) ^ srow) * 8;       // bf16 elem offset in row
    const unsigned short* pA = A  + (size_t)(bm * BM + wave * 8 + srow) * K_TOT + csrc;
    const unsigned short* pB = Bw + (size_t)(bn * BN + wave * 8 + srow) * K_TOT + csrc;
    unsigned short* lw = lds + wave * 8 * 64;       // per-wave LDS row base

    float4v acc[8][4] = {};
    short8 af[4][2];        // A fragments of the current A-half
    short8 bfr[2][2][2];    // B fragments, BOTH halves persistent [nh][ni][ks]

#define STAGE(PG, MATIDX, BUF, H, K0)                                            \
    { _Pragma("unroll")                                                          \
      for (int l = 0; l < 2; ++l) {                                              \
        const unsigned short* g = (PG) + ((size_t)((H) * 128 + l * 64) * K_TOT + (size_t)(K0)); \
        unsigned short* lp = lw + (((BUF) * 4 + (MATIDX) * 2 + (H)) * LDS_HALF) + l * 64 * 64;  \
        __builtin_amdgcn_global_load_lds(                                        \
            (const __attribute__((address_space(1))) unsigned int*)g,            \
            (__attribute__((address_space(3))) unsigned int*)lp, 16, 0, 0);      \
      } }

#define RD_A(RBUF, RMH)                                                          \
    { const unsigned short* Ah = lds + ((RBUF) * 4 + (RMH)) * LDS_HALF;          \
      _Pragma("unroll")                                                          \
      for (int mi = 0; mi < 4; ++mi) {                                           \
        const int r = mi * 32 + wr16 + mrow;                                     \
        _Pragma("unroll")                                                        \
        for (int ks = 0; ks < 2; ++ks)                                           \
          af[mi][ks] = *(const short8*)(Ah + r * 64 + (((ks * 4 + quad) ^ rx) * 8)); \
      } }

#define RD_A1(RBUF, RMH, MI)                                                     \
    { const unsigned short* Ah = lds + ((RBUF) * 4 + (RMH)) * LDS_HALF;          \
      const int r = (MI) * 32 + wr16 + mrow;                                     \
      _Pragma("unroll")                                                          \
      for (int ks = 0; ks < 2; ++ks)                                             \
        af[MI][ks] = *(const short8*)(Ah + r * 64 + (((ks * 4 + quad) ^ rx) * 8)); }

#define RD_B(RBUF, RNH)                                                          \
    { const unsigned short* Bh = lds + ((RBUF) * 4 + 2 + (RNH)) * LDS_HALF;      \
      _Pragma("unroll")                                                          \
      for (int ni = 0; ni < 2; ++ni) {                                           \
        const int r = ni * 64 + wc16 + mrow;                                     \
        _Pragma("unroll")                                                        \
        for (int ks = 0; ks < 2; ++ks)                                           \
          bfr[RNH][ni][ks] = *(const short8*)(Bh + r * 64 + (((ks * 4 + quad) ^ rx) * 8)); \
      } }

// 4 MFMAs consuming af[MI] (x bfr[NH][ni][ks])
#define MFMA_MI(MH, NH, MI)                                                      \
    _Pragma("unroll")                                                            \
    for (int ni = 0; ni < 2; ++ni)                                               \
      _Pragma("unroll")                                                          \
      for (int ks = 0; ks < 2; ++ks)                                             \
        acc[(MH) * 4 + (MI)][(NH) * 2 + ni] =                                    \
            __builtin_amdgcn_mfma_f32_16x16x32_bf16(                             \
                af[MI][ks], bfr[NH][ni][ks], acc[(MH) * 4 + (MI)][(NH) * 2 + ni], 0, 0, 0);

#define BARX { asm volatile("" ::: "memory"); __builtin_amdgcn_s_barrier(); asm volatile("" ::: "memory"); }
#define NOB  ((void)0);
#define WAITV4 asm volatile("s_waitcnt vmcnt(4)" ::: "memory")
#define WAITV0 asm volatile("s_waitcnt vmcnt(0)" ::: "memory")
#define WV4B { WAITV4; BARX }
#define WV0B { WAITV0; BARX }
#define NOWT ((void)0)
#define NOSTG ((void)0)
#define NORD ((void)0)

#define PH_HEAD(BHEAD)                                                           \
    BHEAD                                                                        \
    asm volatile("s_waitcnt lgkmcnt(0)" ::: "memory");                           \
    __builtin_amdgcn_s_setprio(1);

#define PH_TAIL(STG, TAILW, TAILRD)                                              \
    __builtin_amdgcn_s_setprio(0);                                               \
    STG;                                                                         \
    TAILW;                                                                       \
    TAILRD;

// no mid-cluster read
#define PHASE_NR(MH, NH, BHEAD, STG, TAILW, TAILRD)                              \
  { PH_HEAD(BHEAD)                                                               \
    MFMA_MI(MH, NH, 0) MFMA_MI(MH, NH, 1) MFMA_MI(MH, NH, 2) MFMA_MI(MH, NH, 3) \
    PH_TAIL(STG, TAILW, TAILRD) }

// B-read mid-cluster (bfr[RNH] not read by this cluster: RNH == NH^1)
#define PHASE_RB(MH, NH, BHEAD, RBUF, RNH, STG, TAILW)                           \
  { PH_HEAD(BHEAD)                                                               \
    MFMA_MI(MH, NH, 0)                                                           \
    RD_B(RBUF, RNH)                                                              \
    MFMA_MI(MH, NH, 1) MFMA_MI(MH, NH, 2) MFMA_MI(MH, NH, 3)                     \
    PH_TAIL(STG, NOWT, NORD) }

// A-reads interleaved per-mi: [4 MFMAs on af[mi]] then [re-read af[mi]]
#define PHASE_RA(MH, NH, BHEAD, RBUF, RMH, STG, TAILW)                           \
  { PH_HEAD(BHEAD)                                                               \
    MFMA_MI(MH, NH, 0) RD_A1(RBUF, RMH, 0)                                       \
    MFMA_MI(MH, NH, 1) RD_A1(RBUF, RMH, 1)                                       \
    MFMA_MI(MH, NH, 2) RD_A1(RBUF, RMH, 2)                                       \
    MFMA_MI(MH, NH, 3) RD_A1(RBUF, RMH, 3)                                       \
    PH_TAIL(STG, NOWT, NORD) }

    // prologue: tile0 -> buf0 (A0,B1,B0,A1); tile1 -> buf1 (A0,B1);
    // WAITV4 confirms buf0 (buf1's 4 loads stay in flight), barrier, read
    // p0's operands. Entry state == steady-state quad entry (4 outstanding).
    STAGE(pA, 0, 0, 0, 0);
    STAGE(pB, 1, 0, 1, 0);
    STAGE(pB, 1, 0, 0, 0);
    STAGE(pA, 0, 0, 1, 0);
    STAGE(pA, 0, 1, 0, 64);
    STAGE(pB, 1, 1, 1, 64);
    WAITV4;
    BARX
    RD_A(0, 0); RD_B(0, 0);

    int k0b = 64, k0c = 128, k0d = 192;   // k offsets of tiles T+1, T+2, T+3
#pragma unroll 1
    for (int it = 0; it < 15; ++it) {
        PHASE_RB(0, 0, NOB,  0, 1, STAGE(pB, 1, 1, 0, k0b), NOWT)
        PHASE_RA(0, 1, BARX, 0, 1, STAGE(pA, 0, 1, 1, k0b), NOWT)
        PHASE_NR(1, 1, BARX, STAGE(pA, 0, 0, 0, k0c), NOWT, NORD)
        PHASE_NR(1, 0, BARX, STAGE(pB, 1, 0, 1, k0c), WV4B, RD_A(1, 0); RD_B(1, 0))
        PHASE_RB(0, 0, NOB,  1, 1, STAGE(pB, 1, 0, 0, k0c), NOWT)
        PHASE_RA(0, 1, BARX, 1, 1, STAGE(pA, 0, 0, 1, k0c), NOWT)
        PHASE_NR(1, 1, BARX, STAGE(pA, 0, 1, 0, k0d), NOWT, NORD)
        PHASE_NR(1, 0, BARX, STAGE(pB, 1, 1, 1, k0d), WV4B, RD_A(0, 0); RD_B(0, 0))
        k0b += 128; k0c += 128; k0d += 128;
    }
    // tail: tiles 30 (buf0) and 31 (buf1); k0b == 1984 here
    PHASE_RB(0, 0, NOB,  0, 1, STAGE(pB, 1, 1, 0, k0b), NOWT)
    PHASE_RA(0, 1, BARX, 0, 1, STAGE(pA, 0, 1, 1, k0b), NOWT)
    PHASE_NR(1, 1, BARX, NOSTG, NOWT, NORD)
    PHASE_NR(1, 0, BARX, NOSTG, WV0B, RD_A(1, 0); RD_B(1, 0))
    PHASE_RB(0, 0, NOB,  1, 1, NOSTG, NOWT)
    PHASE_RA(0, 1, BARX, 1, 1, NOSTG, NOWT)
    PHASE_NR(1, 1, BARX, NOSTG, NOWT, NORD)
    PHASE_NR(1, 0, BARX, NOSTG, NOWT, NORD)

    // epilogue: C/D layout col = lane&15 (n), row = quad*4 + reg (m); fuse bias
#pragma unroll
    for (int nh = 0; nh < 2; ++nh)
#pragma unroll
        for (int ni = 0; ni < 2; ++ni) {
            const int col = bn * BN + nh * 128 + ni * 64 + wc16 + mrow;
            const float bv = bias[col];
#pragma unroll
            for (int mh = 0; mh < 2; ++mh)
#pragma unroll
                for (int mi = 0; mi < 4; ++mi) {
                    const int row0 = bm * BM + mh * 128 + mi * 32 + wr16 + quad * 4;
#pragma unroll
                    for (int r = 0; r < 4; ++r)
                        C[(size_t)(row0 + r) * N_TOT + col] =
                            acc[mh * 4 + mi][nh * 2 + ni][r] + bv;
                }
        }
#undef PHASE_NR
#undef PHASE_RB
#undef PHASE_RA
#undef PH_HEAD
#undef PH_TAIL
#undef MFMA_MI
#undef STAGE
#undef RD_A
#undef RD_A1
#undef RD_B
#undef BARX
#undef NOB
#undef WAITV4
#undef WAITV0
#undef WV4B
#undef WV0B
#undef NOWT
#undef NOSTG
#undef NORD
}

// ---- Fallback GEMM (proven 128^2 kernel, 32 KiB static LDS) ----
#define FBM 128
#define FBN 128
#define FBK 64
__global__ __launch_bounds__(256) void gemm_bias_kernel_128(
    const unsigned short* __restrict__ A,
    const unsigned short* __restrict__ Bw,
    const float* __restrict__ bias,
    float* __restrict__ C)
{
    __shared__ unsigned short Asm[FBM * FBK];
    __shared__ unsigned short Bsm[FBN * FBK];

    const int tid  = threadIdx.x;
    const int lane = tid & 63;
    const int wave = tid >> 6;
    const int bm = blockIdx.y;
    const int bn = blockIdx.x;

    const int srow_l = lane >> 3;
    const int schunk = ((lane & 7) ^ srow_l) * 8;
    const unsigned short* a_g[4];
    const unsigned short* b_g[4];
    unsigned short* a_l[4];
    unsigned short* b_l[4];
#pragma unroll
    for (int l = 0; l < 4; ++l) {
        const int row = wave * 32 + l * 8 + srow_l;
        a_g[l] = A  + (size_t)(bm * FBM + row) * K_TOT + schunk;
        b_g[l] = Bw + (size_t)(bn * FBN + row) * K_TOT + schunk;
        a_l[l] = Asm + (wave * 32 + l * 8) * FBK;
        b_l[l] = Bsm + (wave * 32 + l * 8) * FBK;
    }

    const int wm = (wave >> 1) * 64;
    const int wn = (wave & 1) * 64;
    const int mrow = lane & 15;
    const int quad = lane >> 4;
    const int rx   = mrow & 7;

    float4v acc[4][4] = {};

    for (int k0 = 0; k0 < K_TOT; k0 += FBK) {
        __syncthreads();
#pragma unroll
        for (int l = 0; l < 4; ++l)
            __builtin_amdgcn_global_load_lds(
                (const __attribute__((address_space(1))) unsigned int*)(a_g[l] + k0),
                (__attribute__((address_space(3))) unsigned int*)a_l[l], 16, 0, 0);
#pragma unroll
        for (int l = 0; l < 4; ++l)
            __builtin_amdgcn_global_load_lds(
                (const __attribute__((address_space(1))) unsigned int*)(b_g[l] + k0),
                (__attribute__((address_space(3))) unsigned int*)b_l[l], 16, 0, 0);
        __syncthreads();

#pragma unroll
        for (int ks = 0; ks < 2; ++ks) {
            short8 af[4], bf_[4];
#pragma unroll
            for (int mi = 0; mi < 4; ++mi) {
                const int r = wm + mi * 16 + mrow;
                const int slot = (ks * 4 + quad) ^ rx;
                af[mi] = *(const short8*)(Asm + r * FBK + slot * 8);
            }
#pragma unroll
            for (int ni = 0; ni < 4; ++ni) {
                const int r = wn + ni * 16 + mrow;
                const int slot = (ks * 4 + quad) ^ rx;
                bf_[ni] = *(const short8*)(Bsm + r * FBK + slot * 8);
            }
#pragma unroll
            for (int mi = 0; mi < 4; ++mi)
#pragma unroll
                for (int ni = 0; ni < 4; ++ni)
                    acc[mi][ni] = __builtin_amdgcn_mfma_f32_16x16x32_bf16(
                        af[mi], bf_[ni], acc[mi][ni], 0, 0, 0);
        }
    }

#pragma unroll
    for (int ni = 0; ni < 4; ++ni) {
        const int col = bn * FBN + wn + ni * 16 + mrow;
        const float bv = bias[col];
#pragma unroll
        for (int mi = 0; mi < 4; ++mi) {
#pragma unroll
            for (int r = 0; r < 4; ++r) {
                const int row = bm * FBM + wm + mi * 16 + quad * 4 + r;
                C[(size_t)row * N_TOT + col] = acc[mi][ni][r] + bv;
            }
        }
    }
}

extern "C" void kernel_launch(void* const* d_in, const int* in_sizes, int n_in,
                              void* d_out, int out_size, void* d_ws, size_t ws_size,
                              hipStream_t stream) {
    const float* x       = (const float*)d_in[0];
    const float* W_val   = (const float*)d_in[1];
    const float* bias    = (const float*)d_in[2];
    const int*   indices = (const int*)d_in[3];
    const int*   indptr  = (const int*)d_in[4];
    float* out = (float*)d_out;

    // workspace: [x_bf16: 16384*2048*2 = 64 MiB][W_bf16: 2048*2048*2 = 8 MiB]
    unsigned short* xb = (unsigned short*)d_ws;
    unsigned short* Wb = xb + (size_t)M_TOT * K_TOT;
    if (ws_size < ((size_t)M_TOT * K_TOT + (size_t)N_TOT * K_TOT) * sizeof(unsigned short))
        return;

    // 128 KiB dynamic LDS requires raising the attribute (host-side config
    // call, capture-safe). If it fails, fall back to the proven 128^2 kernel.
    hipError_t attr_ok = hipFuncSetAttribute(
        reinterpret_cast<const void*>(gemm_bias_kernel_256),
        hipFuncAttributeMaxDynamicSharedMemorySize, 131072);

    // 1) fused prep: densify W + cast x (one dispatch)
    prep_kernel<<<W_BLOCKS + CAST_BLOCKS, 256, 0, stream>>>(x, W_val, indices, indptr, xb, Wb);

    // 2) GEMM + bias
    if (attr_ok == hipSuccess) {
        gemm_bias_kernel_256<<<dim3(512), 512, 131072, stream>>>(xb, Wb, bias, out);
    } else {
        dim3 grid(N_TOT / FBN, M_TOT / FBM);  // (16, 128)
        gemm_bias_kernel_128<<<grid, 256, 0, stream>>>(xb, Wb, bias, out);
    }
}

// Round 7
// 331.784 us; speedup vs baseline: 1.1236x; 1.0176x over previous
//
#include <hip/hip_runtime.h>
#include <hip/hip_bf16.h>
#include <stdint.h>

// Problem dims (fixed by reference)
#define M_TOT 16384   // B*S rows of x
#define K_TOT 2048    // contraction dim (M_DIM)
#define N_TOT 2048    // output cols (N_DIM)

// 256x256 8-phase GEMM geometry
#define BM 256
#define BN 256
#define BK 64
#define LDS_HALF (128 * 64)   // shorts per half-tile [128 rows][64 k]

#define W_BLOCKS 2048      // prep: blocks [0, 2048) build W rows
#define CAST_BLOCKS 16384  // prep: blocks [2048, 18432) cast x

typedef __attribute__((ext_vector_type(8))) short short8;
typedef __attribute__((ext_vector_type(4))) float float4v;
typedef __attribute__((ext_vector_type(8))) unsigned short ushort8;

__device__ __forceinline__ unsigned short f2bf_rne(float f) {
    union { float f; unsigned u; } a; a.f = f;
    unsigned r = a.u + 0x7FFFu + ((a.u >> 16) & 1u);  // round-to-nearest-even
    return (unsigned short)(r >> 16);
}

// ---- Prep: W densify (zero+scatter) AND x fp32->bf16 cast, ONE dispatch ----
__global__ __launch_bounds__(256) void prep_kernel(
    const float* __restrict__ x,
    const float* __restrict__ val, const int* __restrict__ idx,
    const int* __restrict__ indptr,
    unsigned short* __restrict__ xb, unsigned short* __restrict__ Wb) {
    const int b = blockIdx.x;
    if (b < W_BLOCKS) {
        const int n = b;
        unsigned short* row = Wb + (size_t)n * K_TOT;
        ushort8 z = {0, 0, 0, 0, 0, 0, 0, 0};
        ((ushort8*)row)[threadIdx.x] = z;
        __syncthreads();
        const int s = indptr[n], e = indptr[n + 1];
        for (int j = s + (int)threadIdx.x; j < e; j += (int)blockDim.x)
            row[idx[j]] = f2bf_rne(val[j]);
    } else {
        const int i = (b - W_BLOCKS) * 256 + (int)threadIdx.x;  // 8-float chunk id
        const float4* xf = (const float4*)x;
        float4 a = xf[2 * i];
        float4 c = xf[2 * i + 1];
        ushort8 o;
        o[0] = f2bf_rne(a.x); o[1] = f2bf_rne(a.y); o[2] = f2bf_rne(a.z); o[3] = f2bf_rne(a.w);
        o[4] = f2bf_rne(c.x); o[5] = f2bf_rne(c.y); o[6] = f2bf_rne(c.z); o[7] = f2bf_rne(c.w);
        ((ushort8*)xb)[i] = o;
    }
}

// ---- 256x256 8-phase GEMM: C = A * W^T + bias ----
// Round-5 skeleton (best measured: 121.4 us) with ONE change: the MFMA
// cluster is emitted ks-OUTERMOST. Previous rounds used ks-innermost, making
// every second MFMA RAW-dependent on its immediate predecessor (same
// acc[mi][ni], ks=0 -> ks=1); with in-order issue each dependent MFMA stalls
// the wave for full MFMA latency and blocks everything behind it (reads,
// stage, barrier) -> measured ~500 cyc/phase of slack over the 620-cyc
// matrix-pipe floor. ks-outer gives 8 independent MFMAs then 8 partners,
// each 8 instructions (>= pipe latency) from its producer.
//
// Schedule per iteration (tiles T=2i buf0, T+1 buf1; reads at phase TAIL
// for the NEXT phase; lgkmcnt(0) at phase head drains them):
//   p0 STG B0(T+1)->b1   RD B1<-b0
//   p1 STG A1(T+1)->b1   RD A1<-b0
//   p2 STG A0(T+2)->b0   --
//   p3 STG B1(T+2)->b0   WAITV4+bar, RD A0,B0<-b1
//   p4 STG B0(T+2)->b0   RD B1<-b1
//   p5 STG A1(T+2)->b0   RD A1<-b1
//   p6 STG A0(T+3)->b1   --
//   p7 STG B1(T+3)->b1   WAITV4+bar, RD A0,B0<-b0
// vmcnt ledger: each buf-quad entered with exactly 4 outstanding loads;
// WAITV4 after the quad's 4 stages confirms exactly the halves the next quad
// pre-reads. All 8 stage-vs-last-reader margins (>=1 lgkm0 drain + >=1
// barrier) hand-verified. Swizzle: LDS slot s of row r holds global 16B
// chunk s^(r&7) (pre-swizzled global source; LDS dest lane-linear; measured
// SQ_LDS_BANK_CONFLICT = 0).
__global__ __launch_bounds__(512, 2) void gemm_bias_kernel_256(
    const unsigned short* __restrict__ A,   // [M_TOT][K_TOT] bf16
    const unsigned short* __restrict__ Bw,  // [N_TOT][K_TOT] bf16
    const float* __restrict__ bias,         // [N_TOT]
    float* __restrict__ C)                  // [M_TOT][N_TOT] fp32
{
    extern __shared__ unsigned short lds[];  // 131072 B dynamic

    const int tid  = threadIdx.x;
    const int lane = tid & 63;
    const int wave = tid >> 6;              // 0..7

    // XCD-aware bijective swizzle: 512 blocks, 64 per XCD, bn fastest inside
    const int raw = blockIdx.x;
    const int lid = (raw & 7) * 64 + (raw >> 3);
    const int bm = lid >> 3;                // 0..63
    const int bn = lid & 7;                 // 0..7

    const int wrow = wave >> 2;             // 0..1
    const int wcol = wave & 3;              // 0..3
    const int wr16 = wrow * 16;
    const int wc16 = wcol * 16;
    const int mrow = lane & 15;
    const int quad = lane >> 4;
    const int rx   = mrow & 7;              // row&7 for swizzle (bases %8==0)

    // staging: per global_load_lds, wave covers 8 rows x 8 chunks of 16B;
    // source chunk = (lane&7)^(row&7) pre-swizzled, LDS dest lane-linear.
    const int srow = lane >> 3;                     // 0..7
    const int csrc = ((lane & 7) ^ srow) * 8;       // bf16 elem offset in row
    const unsigned short* pA = A  + (size_t)(bm * BM + wave * 8 + srow) * K_TOT + csrc;
    const unsigned short* pB = Bw + (size_t)(bn * BN + wave * 8 + srow) * K_TOT + csrc;
    unsigned short* lw = lds + wave * 8 * 64;       // per-wave LDS row base

    float4v acc[8][4] = {};
    short8 af[4][2];        // A fragments of the current A-half
    short8 bfr[2][2][2];    // B fragments, BOTH halves persistent [nh][ni][ks]

#define STAGE(PG, MATIDX, BUF, H, K0)                                            \
    { _Pragma("unroll")                                                          \
      for (int l = 0; l < 2; ++l) {                                              \
        const unsigned short* g = (PG) + ((size_t)((H) * 128 + l * 64) * K_TOT + (size_t)(K0)); \
        unsigned short* lp = lw + (((BUF) * 4 + (MATIDX) * 2 + (H)) * LDS_HALF) + l * 64 * 64;  \
        __builtin_amdgcn_global_load_lds(                                        \
            (const __attribute__((address_space(1))) unsigned int*)g,            \
            (__attribute__((address_space(3))) unsigned int*)lp, 16, 0, 0);      \
      } }

#define RD_A(RBUF, RMH)                                                          \
    { const unsigned short* Ah = lds + ((RBUF) * 4 + (RMH)) * LDS_HALF;          \
      _Pragma("unroll")                                                          \
      for (int mi = 0; mi < 4; ++mi) {                                           \
        const int r = mi * 32 + wr16 + mrow;                                     \
        _Pragma("unroll")                                                        \
        for (int ks = 0; ks < 2; ++ks)                                           \
          af[mi][ks] = *(const short8*)(Ah + r * 64 + (((ks * 4 + quad) ^ rx) * 8)); \
      } }

#define RD_B(RBUF, RNH)                                                          \
    { const unsigned short* Bh = lds + ((RBUF) * 4 + 2 + (RNH)) * LDS_HALF;      \
      _Pragma("unroll")                                                          \
      for (int ni = 0; ni < 2; ++ni) {                                           \
        const int r = ni * 64 + wc16 + mrow;                                     \
        _Pragma("unroll")                                                        \
        for (int ks = 0; ks < 2; ++ks)                                           \
          bfr[RNH][ni][ks] = *(const short8*)(Bh + r * 64 + (((ks * 4 + quad) ^ rx) * 8)); \
      } }

#define BARX { asm volatile("" ::: "memory"); __builtin_amdgcn_s_barrier(); asm volatile("" ::: "memory"); }
#define NOB  ((void)0);
#define WAITV4 asm volatile("s_waitcnt vmcnt(4)" ::: "memory")
#define WAITV0 asm volatile("s_waitcnt vmcnt(0)" ::: "memory")
#define WV4B { WAITV4; BARX }
#define WV0B { WAITV0; BARX }
#define NOWT ((void)0)
#define NOSTG ((void)0)
#define NORD ((void)0)

// PHASE: [BHEAD][lgkm0][MFMA cluster, ks-OUTER][stage][tail-wait][pre-reads]
#define PHASE(MH, NH, BHEAD, STG, TAILW, RDS)                                    \
  {                                                                              \
    BHEAD                                                                        \
    asm volatile("s_waitcnt lgkmcnt(0)" ::: "memory");                           \
    __builtin_amdgcn_s_setprio(1);                                               \
    _Pragma("unroll")                                                            \
    for (int ks = 0; ks < 2; ++ks)                                               \
      _Pragma("unroll")                                                          \
      for (int mi = 0; mi < 4; ++mi)                                             \
        _Pragma("unroll")                                                        \
        for (int ni = 0; ni < 2; ++ni)                                           \
          acc[(MH) * 4 + mi][(NH) * 2 + ni] =                                    \
              __builtin_amdgcn_mfma_f32_16x16x32_bf16(                           \
                  af[mi][ks], bfr[NH][ni][ks], acc[(MH) * 4 + mi][(NH) * 2 + ni], 0, 0, 0); \
    __builtin_amdgcn_s_setprio(0);                                               \
    STG;                                                                         \
    TAILW;                                                                       \
    RDS;                                                                         \
  }

    // prologue: tile0 -> buf0 (A0,B1,B0,A1); tile1 -> buf1 (A0,B1);
    // WAITV4 confirms buf0 (buf1's 4 loads stay in flight), barrier, read
    // p0's operands. Entry state == steady-state quad entry (4 outstanding).
    STAGE(pA, 0, 0, 0, 0);
    STAGE(pB, 1, 0, 1, 0);
    STAGE(pB, 1, 0, 0, 0);
    STAGE(pA, 0, 0, 1, 0);
    STAGE(pA, 0, 1, 0, 64);
    STAGE(pB, 1, 1, 1, 64);
    WAITV4;
    BARX
    RD_A(0, 0); RD_B(0, 0);

    int k0b = 64, k0c = 128, k0d = 192;   // k offsets of tiles T+1, T+2, T+3
#pragma unroll 1
    for (int it = 0; it < 15; ++it) {
        PHASE(0, 0, NOB,  STAGE(pB, 1, 1, 0, k0b), NOWT, RD_B(0, 1))
        PHASE(0, 1, BARX, STAGE(pA, 0, 1, 1, k0b), NOWT, RD_A(0, 1))
        PHASE(1, 1, BARX, STAGE(pA, 0, 0, 0, k0c), NOWT, NORD)
        PHASE(1, 0, BARX, STAGE(pB, 1, 0, 1, k0c), WV4B, RD_A(1, 0); RD_B(1, 0))
        PHASE(0, 0, NOB,  STAGE(pB, 1, 0, 0, k0c), NOWT, RD_B(1, 1))
        PHASE(0, 1, BARX, STAGE(pA, 0, 0, 1, k0c), NOWT, RD_A(1, 1))
        PHASE(1, 1, BARX, STAGE(pA, 0, 1, 0, k0d), NOWT, NORD)
        PHASE(1, 0, BARX, STAGE(pB, 1, 1, 1, k0d), WV4B, RD_A(0, 0); RD_B(0, 0))
        k0b += 128; k0c += 128; k0d += 128;
    }
    // tail: tiles 30 (buf0) and 31 (buf1); k0b == 1984 here
    PHASE(0, 0, NOB,  STAGE(pB, 1, 1, 0, k0b), NOWT, RD_B(0, 1))
    PHASE(0, 1, BARX, STAGE(pA, 0, 1, 1, k0b), NOWT, RD_A(0, 1))
    PHASE(1, 1, BARX, NOSTG, NOWT, NORD)
    PHASE(1, 0, BARX, NOSTG, WV0B, RD_A(1, 0); RD_B(1, 0))
    PHASE(0, 0, NOB,  NOSTG, NOWT, RD_B(1, 1))
    PHASE(0, 1, BARX, NOSTG, NOWT, RD_A(1, 1))
    PHASE(1, 1, BARX, NOSTG, NOWT, NORD)
    PHASE(1, 0, BARX, NOSTG, NOWT, NORD)

    // epilogue: C/D layout col = lane&15 (n), row = quad*4 + reg (m); fuse bias
#pragma unroll
    for (int nh = 0; nh < 2; ++nh)
#pragma unroll
        for (int ni = 0; ni < 2; ++ni) {
            const int col = bn * BN + nh * 128 + ni * 64 + wc16 + mrow;
            const float bv = bias[col];
#pragma unroll
            for (int mh = 0; mh < 2; ++mh)
#pragma unroll
                for (int mi = 0; mi < 4; ++mi) {
                    const int row0 = bm * BM + mh * 128 + mi * 32 + wr16 + quad * 4;
#pragma unroll
                    for (int r = 0; r < 4; ++r)
                        C[(size_t)(row0 + r) * N_TOT + col] =
                            acc[mh * 4 + mi][nh * 2 + ni][r] + bv;
                }
        }
#undef PHASE
#undef STAGE
#undef RD_A
#undef RD_B
#undef BARX
#undef NOB
#undef WAITV4
#undef WAITV0
#undef WV4B
#undef WV0B
#undef NOWT
#undef NOSTG
#undef NORD
}

// ---- Fallback GEMM (proven 128^2 kernel, 32 KiB static LDS) ----
#define FBM 128
#define FBN 128
#define FBK 64
__global__ __launch_bounds__(256) void gemm_bias_kernel_128(
    const unsigned short* __restrict__ A,
    const unsigned short* __restrict__ Bw,
    const float* __restrict__ bias,
    float* __restrict__ C)
{
    __shared__ unsigned short Asm[FBM * FBK];
    __shared__ unsigned short Bsm[FBN * FBK];

    const int tid  = threadIdx.x;
    const int lane = tid & 63;
    const int wave = tid >> 6;
    const int bm = blockIdx.y;
    const int bn = blockIdx.x;

    const int srow_l = lane >> 3;
    const int schunk = ((lane & 7) ^ srow_l) * 8;
    const unsigned short* a_g[4];
    const unsigned short* b_g[4];
    unsigned short* a_l[4];
    unsigned short* b_l[4];
#pragma unroll
    for (int l = 0; l < 4; ++l) {
        const int row = wave * 32 + l * 8 + srow_l;
        a_g[l] = A  + (size_t)(bm * FBM + row) * K_TOT + schunk;
        b_g[l] = Bw + (size_t)(bn * FBN + row) * K_TOT + schunk;
        a_l[l] = Asm + (wave * 32 + l * 8) * FBK;
        b_l[l] = Bsm + (wave * 32 + l * 8) * FBK;
    }

    const int wm = (wave >> 1) * 64;
    const int wn = (wave & 1) * 64;
    const int mrow = lane & 15;
    const int quad = lane >> 4;
    const int rx   = mrow & 7;

    float4v acc[4][4] = {};

    for (int k0 = 0; k0 < K_TOT; k0 += FBK) {
        __syncthreads();
#pragma unroll
        for (int l = 0; l < 4; ++l)
            __builtin_amdgcn_global_load_lds(
                (const __attribute__((address_space(1))) unsigned int*)(a_g[l] + k0),
                (__attribute__((address_space(3))) unsigned int*)a_l[l], 16, 0, 0);
#pragma unroll
        for (int l = 0; l < 4; ++l)
            __builtin_amdgcn_global_load_lds(
                (const __attribute__((address_space(1))) unsigned int*)(b_g[l] + k0),
                (__attribute__((address_space(3))) unsigned int*)b_l[l], 16, 0, 0);
        __syncthreads();

#pragma unroll
        for (int ks = 0; ks < 2; ++ks) {
            short8 af[4], bf_[4];
#pragma unroll
            for (int mi = 0; mi < 4; ++mi) {
                const int r = wm + mi * 16 + mrow;
                const int slot = (ks * 4 + quad) ^ rx;
                af[mi] = *(const short8*)(Asm + r * FBK + slot * 8);
            }
#pragma unroll
            for (int ni = 0; ni < 4; ++ni) {
                const int r = wn + ni * 16 + mrow;
                const int slot = (ks * 4 + quad) ^ rx;
                bf_[ni] = *(const short8*)(Bsm + r * FBK + slot * 8);
            }
#pragma unroll
            for (int mi = 0; mi < 4; ++mi)
#pragma unroll
                for (int ni = 0; ni < 4; ++ni)
                    acc[mi][ni] = __builtin_amdgcn_mfma_f32_16x16x32_bf16(
                        af[mi], bf_[ni], acc[mi][ni], 0, 0, 0);
        }
    }

#pragma unroll
    for (int ni = 0; ni < 4; ++ni) {
        const int col = bn * FBN + wn + ni * 16 + mrow;
        const float bv = bias[col];
#pragma unroll
        for (int mi = 0; mi < 4; ++mi) {
#pragma unroll
            for (int r = 0; r < 4; ++r) {
                const int row = bm * FBM + wm + mi * 16 + quad * 4 + r;
                C[(size_t)row * N_TOT + col] = acc[mi][ni][r] + bv;
            }
        }
    }
}

extern "C" void kernel_launch(void* const* d_in, const int* in_sizes, int n_in,
                              void* d_out, int out_size, void* d_ws, size_t ws_size,
                              hipStream_t stream) {
    const float* x       = (const float*)d_in[0];
    const float* W_val   = (const float*)d_in[1];
    const float* bias    = (const float*)d_in[2];
    const int*   indices = (const int*)d_in[3];
    const int*   indptr  = (const int*)d_in[4];
    float* out = (float*)d_out;

    // workspace: [x_bf16: 16384*2048*2 = 64 MiB][W_bf16: 2048*2048*2 = 8 MiB]
    unsigned short* xb = (unsigned short*)d_ws;
    unsigned short* Wb = xb + (size_t)M_TOT * K_TOT;
    if (ws_size < ((size_t)M_TOT * K_TOT + (size_t)N_TOT * K_TOT) * sizeof(unsigned short))
        return;

    // 128 KiB dynamic LDS requires raising the attribute (host-side config
    // call, capture-safe). If it fails, fall back to the proven 128^2 kernel.
    hipError_t attr_ok = hipFuncSetAttribute(
        reinterpret_cast<const void*>(gemm_bias_kernel_256),
        hipFuncAttributeMaxDynamicSharedMemorySize, 131072);

    // 1) fused prep: densify W + cast x (one dispatch)
    prep_kernel<<<W_BLOCKS + CAST_BLOCKS, 256, 0, stream>>>(x, W_val, indices, indptr, xb, Wb);

    // 2) GEMM + bias
    if (attr_ok == hipSuccess) {
        gemm_bias_kernel_256<<<dim3(512), 512, 131072, stream>>>(xb, Wb, bias, out);
    } else {
        dim3 grid(N_TOT / FBN, M_TOT / FBM);  // (16, 128)
        gemm_bias_kernel_128<<<grid, 256, 0, stream>>>(xb, Wb, bias, out);
    }
}